// Round 10
// baseline (250.271 us; speedup 1.0000x reference)
//
#include <hip/hip_runtime.h>

typedef __bf16 bf16_t;
typedef __bf16 bf16x4 __attribute__((ext_vector_type(4)));
typedef __bf16 bf16x8 __attribute__((ext_vector_type(8)));
typedef float f32x4 __attribute__((ext_vector_type(4)));
typedef unsigned long long u64;

#define MFMA16(a, b, c) __builtin_amdgcn_mfma_f32_16x16x32_bf16((a), (b), (c), 0, 0, 0)

// load 8 consecutive elements as bf16x8 (fp32 source converted)
__device__ inline bf16x8 load8(const float* p) {
    const f32x4 a = *(const f32x4*)p;
    const f32x4 b = *(const f32x4*)(p + 4);
    bf16x8 r;
#pragma unroll
    for (int i = 0; i < 4; i++) { r[i] = (bf16_t)a[i]; r[4 + i] = (bf16_t)b[i]; }
    return r;
}
__device__ inline bf16x8 load8(const bf16_t* p) { return *(const bf16x8*)p; }

// 8-byte cross-lane shuffle of a packed bf16x4
__device__ inline bf16x4 shfl4(bf16x4 v, int src) {
    u64 x;
    __builtin_memcpy(&x, &v, 8);
    x = __shfl(x, src, 64);
    bf16x4 r;
    __builtin_memcpy(&r, &x, 8);
    return r;
}

// ---------------------------------------------------------------------------
// K/V swizzled layouts (MFMA-fragment order -> attn loads are base+lane*16):
//   k_sw: elem offset = ((bh*128 + t>>4)*2 + (d>>5))*512 + ((t&15)+16*((d&31)>>3))*8 + (d&7)
//   v_sw: elem offset = ((bh*64 + t>>5)*4 + (d>>4))*512 + ((d&15)+16*((t&31)>>3))*8 + (t&7)
// ---------------------------------------------------------------------------

// GEMM: C[M x N] = A[M x K] * B[N x K]^T,  K = 1024, fp32 (or bf16 ws) inputs.
// 128x128 tile, BK=32, 256 threads (4 waves), wave = 64x64 = 4x4 MFMA tiles.
// 1-deep software pipeline: next K-tile loads issued after the barrier, so
// the current tile's ds_reads + 16 MFMAs cover global latency.
// LDS row stride 40 (not 32): 80B = 20-bank stride, gcd(20,32)=4 -> 2-way
// (free) instead of 8-way bank conflicts on fragment reads.
// MODE 0: store C row-major fp32 to outp (N = NDIM)
// MODE 1: qkv scatter: j<16 -> q_ws[bh][t][d]; j<32 -> k_sw; else v_sw
template <int MODE, int NDIM, typename TA>
__global__ __launch_bounds__(256) void gemm_bt(const TA* __restrict__ A,
                                               const float* __restrict__ B,
                                               float* __restrict__ outp,
                                               bf16_t* __restrict__ q_ws,
                                               bf16_t* __restrict__ k_ws,
                                               bf16_t* __restrict__ v_ws) {
    constexpr int K = 1024;
    constexpr int LW = 40;  // padded LDS row stride (elements)
    __shared__ __align__(16) bf16_t As[128 * LW];
    __shared__ __align__(16) bf16_t Bs[128 * LW];

    const int tid = threadIdx.x;
    const int w = tid >> 6;
    const int lane = tid & 63;
    const int lr = lane & 15;
    const int quad = lane >> 4;
    const int m0 = blockIdx.y * 128;
    const int n0 = blockIdx.x * 128;
    const int wm = (w & 1) * 64;
    const int wn = (w >> 1) * 64;

    const int srow = tid >> 2;
    const int skk = (tid & 3) * 8;
    const TA* gA0 = A + (size_t)(m0 + srow) * K + skk;
    const TA* gA1 = gA0 + (size_t)64 * K;
    const float* gB0 = B + (size_t)(n0 + srow) * K + skk;
    const float* gB1 = gB0 + (size_t)64 * K;

    f32x4 acc[4][4] = {};

    // pipeline prologue: first K-tile into registers
    bf16x8 ra0 = load8(gA0);
    bf16x8 ra1 = load8(gA1);
    bf16x8 rb0 = load8(gB0);
    bf16x8 rb1 = load8(gB1);

    for (int k0 = 0; k0 < K; k0 += 32) {
        __syncthreads();  // previous iteration done reading LDS
        *(bf16x8*)&As[srow * LW + skk] = ra0;
        *(bf16x8*)&As[(64 + srow) * LW + skk] = ra1;
        *(bf16x8*)&Bs[srow * LW + skk] = rb0;
        *(bf16x8*)&Bs[(64 + srow) * LW + skk] = rb1;
        __syncthreads();  // LDS tile ready

        // prefetch next K-tile (wrapped on last iter: harmless L2-hit reload)
        const int k1 = (k0 + 32 < K) ? k0 + 32 : 0;
        ra0 = load8(gA0 + k1);
        ra1 = load8(gA1 + k1);
        rb0 = load8(gB0 + k1);
        rb1 = load8(gB1 + k1);

        bf16x8 af[4], bfm[4];
#pragma unroll
        for (int im = 0; im < 4; im++)
            af[im] = *(const bf16x8*)&As[(wm + im * 16 + lr) * LW + quad * 8];
#pragma unroll
        for (int in = 0; in < 4; in++)
            bfm[in] = *(const bf16x8*)&Bs[(wn + in * 16 + lr) * LW + quad * 8];
#pragma unroll
        for (int im = 0; im < 4; im++)
#pragma unroll
            for (int in = 0; in < 4; in++)
                acc[im][in] = MFMA16(af[im], bfm[in], acc[im][in]);
    }

#pragma unroll
    for (int im = 0; im < 4; im++) {
#pragma unroll
        for (int in = 0; in < 4; in++) {
#pragma unroll
            for (int r = 0; r < 4; r++) {
                const int m = m0 + wm + im * 16 + quad * 4 + r;
                const int n = n0 + wn + in * 16 + lr;
                const float v = acc[im][in][r];
                if constexpr (MODE == 0) {
                    outp[(size_t)m * NDIM + n] = v;
                } else {
                    const int b = m >> 11;      // T = 2048
                    const int t = m & 2047;
                    const int j = n >> 6;       // which of 48 head-slots
                    const int d = n & 63;
                    if (j < 16) {
                        q_ws[(((size_t)(b * 16 + j) * 2048) + t) * 64 + d] = (bf16_t)v;
                    } else if (j < 32) {
                        const int bh = b * 16 + (j - 16);
                        const size_t off =
                            ((size_t)(bh * 128 + (t >> 4)) * 2 + (d >> 5)) * 512 +
                            ((t & 15) + ((d & 31) >> 3) * 16) * 8 + (d & 7);
                        k_ws[off] = (bf16_t)v;
                    } else {
                        const int bh = b * 16 + (j - 32);
                        const size_t off =
                            ((size_t)(bh * 64 + (t >> 5)) * 4 + (d >> 4)) * 512 +
                            ((d & 15) + ((t & 31) >> 3) * 16) * 8 + (t & 7);
                        v_ws[off] = (bf16_t)v;
                    }
                }
            }
        }
    }
}

// ---------------------------------------------------------------------------
// RoPE in place on q_ws ([bh][t][64]) and k_sw (swizzled). Pairs (d, d+32):
// in k_sw they differ only by the `half` chunk -> +512 elements.
// Folds 0.125 * log2(e) into q so attention can use exp2.
// idx bits: d[0:5) t[5:16) bh[16:21) isk[21]
// ---------------------------------------------------------------------------
__global__ __launch_bounds__(256) void rope_kernel(bf16_t* __restrict__ q_ws,
                                                   bf16_t* __restrict__ k_ws,
                                                   const float* __restrict__ cosb,
                                                   const float* __restrict__ sinb) {
    const int idx = blockIdx.x * 256 + threadIdx.x;
    const int d = idx & 31;
    const int t = (idx >> 5) & 2047;
    const int bh = (idx >> 16) & 31;
    const int isk = idx >> 21;
    const float c = cosb[t * 64 + d];
    const float s = sinb[t * 64 + d];
    if (isk) {
        const size_t base = ((size_t)(bh * 128 + (t >> 4)) * 2) * 512 +
                            ((t & 15) + (d >> 3) * 16) * 8 + (d & 7);
        const float x1 = (float)k_ws[base];
        const float x2 = (float)k_ws[base + 512];
        k_ws[base] = (bf16_t)(x1 * c - x2 * s);
        k_ws[base + 512] = (bf16_t)(x2 * c + x1 * s);
    } else {
        const size_t base = ((size_t)bh * 2048 + t) * 64 + d;
        const float x1 = (float)q_ws[base];
        const float x2 = (float)q_ws[base + 32];
        const float qs = 0.125f * 1.44269504089f;  // fold log2(e): attn uses exp2
        q_ws[base] = (bf16_t)((x1 * c - x2 * s) * qs);
        q_ws[base + 32] = (bf16_t)((x2 * c + x1 * s) * qs);
    }
}

// ---------------------------------------------------------------------------
// Flash attention: transposed-score, barrier/LDS/max-free, coalesced swizzled
// K/V loads (1KB contiguous per instruction) + register double-buffer K
// prefetch across the back-edge (V issued at body top, consumed at bottom).
// Grid: blockIdx.x = qt'*32 + bh, qt = 31-qt' (LPT). 4 independent waves;
// wave w owns queries [qt*64+16w, +16).
// ---------------------------------------------------------------------------
__global__ __launch_bounds__(256) void attn_kernel(const bf16_t* __restrict__ q_ws,
                                                   const bf16_t* __restrict__ k_ws,
                                                   const bf16_t* __restrict__ v_ws,
                                                   bf16_t* __restrict__ ctx) {
    const int tid = threadIdx.x;
    const int w = tid >> 6;
    const int lane = tid & 63;
    const int lr = lane & 15;
    const int quad = lane >> 4;
    const int bh = blockIdx.x & 31;
    const int qt = 31 - (blockIdx.x >> 5);  // LPT
    const int trow = qt * 64 + w * 16;
    const int query = trow + lr;

    const bf16_t* qb = q_ws + ((size_t)bh * 2048 + trow + lr) * 64 + quad * 8;
    const bf16x8 qlo = *(const bf16x8*)qb;
    const bf16x8 qhi = *(const bf16x8*)(qb + 32);

    const bf16_t* kbase = k_ws + (size_t)bh * 131072 + lane * 8;
    const bf16_t* vbase = v_ws + (size_t)bh * 131072 + lane * 8;

    f32x4 o[4] = {};
    float lrun = 0.0f;

    const int srcLow = ((quad & 1) << 5) + lr;
    const int srcHigh = srcLow + 16;
    const bool loSel = (quad < 2);

    // K chunk address: ((kb*4+n)*2 + half)*512 ; V: ((kb*2+hh)*4 + n)*512
    bf16x8 kc[8];
#pragma unroll
    for (int n = 0; n < 4; n++) {
        kc[2 * n] = *(const bf16x8*)(kbase + (size_t)(n * 2) * 512);
        kc[2 * n + 1] = *(const bf16x8*)(kbase + (size_t)(n * 2 + 1) * 512);
    }

    for (int kb = 0; kb <= qt; kb++) {
        // V(kb) loads: consumed at body end -> full-body latency cover
        bf16x8 vv[2][4];
#pragma unroll
        for (int hh = 0; hh < 2; hh++)
#pragma unroll
            for (int n = 0; n < 4; n++)
                vv[hh][n] = *(const bf16x8*)(vbase +
                    (size_t)((kb * 2 + hh) * 4 + n) * 512);

        // K(kb+1) prefetch (uniform; last iter harmlessly reloads qt)
        const int kbn = (kb < qt) ? kb + 1 : kb;
        bf16x8 kn[8];
#pragma unroll
        for (int n = 0; n < 4; n++) {
            kn[2 * n] = *(const bf16x8*)(kbase + (size_t)((kbn * 4 + n) * 2) * 512);
            kn[2 * n + 1] = *(const bf16x8*)(kbase + (size_t)((kbn * 4 + n) * 2 + 1) * 512);
        }

        const int u0 = kb * 64;
        f32x4 s[4];
#pragma unroll
        for (int n = 0; n < 4; n++) {
            const f32x4 z = {};
            s[n] = MFMA16(kc[2 * n], qlo, z);
            s[n] = MFMA16(kc[2 * n + 1], qhi, s[n]);
        }

        if (kb == qt) {  // diagonal 64-key block: causal mask (key > query)
#pragma unroll
            for (int n = 0; n < 4; n++)
#pragma unroll
                for (int r = 0; r < 4; r++)
                    if (u0 + n * 16 + quad * 4 + r > query) s[n][r] = -1e9f;
        }

        f32x4 p[4];
#pragma unroll
        for (int n = 0; n < 4; n++)
#pragma unroll
            for (int r = 0; r < 4; r++) p[n][r] = exp2f(s[n][r]);

        lrun += ((p[0][0] + p[0][1]) + (p[0][2] + p[0][3])) +
                ((p[1][0] + p[1][1]) + (p[1][2] + p[1][3])) +
                ((p[2][0] + p[2][1]) + (p[2][2] + p[2][3])) +
                ((p[3][0] + p[3][1]) + (p[3][2] + p[3][3]));

        bf16x4 pb[4];
#pragma unroll
        for (int n = 0; n < 4; n++)
#pragma unroll
            for (int r = 0; r < 4; r++) pb[n][r] = (bf16_t)p[n][r];

#pragma unroll
        for (int hh = 0; hh < 2; hh++) {  // 32-key halves
            const bf16x4 a0 = shfl4(pb[2 * hh], srcLow);
            const bf16x4 a1 = shfl4(pb[2 * hh + 1], srcLow);
            const bf16x4 b0 = shfl4(pb[2 * hh], srcHigh);
            const bf16x4 b1 = shfl4(pb[2 * hh + 1], srcHigh);
            const bf16x4 lo = loSel ? a0 : a1;
            const bf16x4 hi = loSel ? b0 : b1;
            bf16x8 pf;
#pragma unroll
            for (int r = 0; r < 4; r++) { pf[r] = lo[r]; pf[4 + r] = hi[r]; }

#pragma unroll
            for (int n = 0; n < 4; n++)
                o[n] = MFMA16(vv[hh][n], pf, o[n]);
        }

#pragma unroll
        for (int i = 0; i < 8; i++) kc[i] = kn[i];
    }

    // final l reduction across the 4 quads holding this query's keys
    lrun += __shfl_xor(lrun, 16);
    lrun += __shfl_xor(lrun, 32);

    // epilogue: lane owns query=trow+lr, d = n*16 + quad*4 + r
    const int b = bh >> 4;
    const int hd = bh & 15;
    const float inv = 1.0f / fmaxf(lrun, 1e-30f);
    const size_t base = ((size_t)b * 2048 + query) * 1024 + hd * 64 + quad * 4;
#pragma unroll
    for (int n = 0; n < 4; n++) {
        bf16x4 ob;
#pragma unroll
        for (int r = 0; r < 4; r++) ob[r] = (bf16_t)(o[n][r] * inv);
        *(bf16x4*)&ctx[base + n * 16] = ob;
    }
}

// ---------------------------------------------------------------------------
// Launcher. Inputs fp32, output fp32. ws: q_ws[0,8M) k_sw[8M,16M) v_sw[16M,24M)
// ctx[24M,32M)
// ---------------------------------------------------------------------------
extern "C" void kernel_launch(void* const* d_in, const int* in_sizes, int n_in,
                              void* d_out, int out_size, void* d_ws, size_t ws_size,
                              hipStream_t stream) {
    const float* hs = (const float*)d_in[0];
    const float* cosb = (const float*)d_in[1];
    const float* sinb = (const float*)d_in[2];
    const float* wqkv = (const float*)d_in[3];
    const float* wo = (const float*)d_in[4];
    float* out = (float*)d_out;

    char* ws = (char*)d_ws;
    bf16_t* q_ws = (bf16_t*)(ws);
    bf16_t* k_ws = (bf16_t*)(ws + (size_t)(8u << 20));
    bf16_t* v_ws = (bf16_t*)(ws + (size_t)(16u << 20));
    bf16_t* ctx = (bf16_t*)(ws + (size_t)(24u << 20));

    const dim3 blk(256);

    // 1) QKV projection + scatter:  M=4096, N=3072, K=1024
    gemm_bt<1, 3072><<<dim3(24, 32), blk, 0, stream>>>(hs, wqkv, nullptr,
                                                       q_ws, k_ws, v_ws);

    // 2) RoPE in place on q, k (+ fold scale*log2e into q)
    rope_kernel<<<dim3(16384), blk, 0, stream>>>(q_ws, k_ws, cosb, sinb);

    // 3) Flash attention -> ctx [B,T,1024] (bf16)
    attn_kernel<<<dim3(1024), blk, 0, stream>>>(q_ws, k_ws, v_ws, ctx);

    // 4) Output projection: M=4096, N=1024, K=1024 (A = ctx bf16)
    gemm_bt<0, 1024><<<dim3(8, 32), blk, 0, stream>>>(ctx, wo, out,
                                                      nullptr, nullptr, nullptr);
}

// Round 11
// 200.234 us; speedup vs baseline: 1.2499x; 1.2499x over previous
//
#include <hip/hip_runtime.h>

typedef __bf16 bf16_t;
typedef __bf16 bf16x4 __attribute__((ext_vector_type(4)));
typedef __bf16 bf16x8 __attribute__((ext_vector_type(8)));
typedef float f32x4 __attribute__((ext_vector_type(4)));
typedef unsigned long long u64;

#define MFMA16(a, b, c) __builtin_amdgcn_mfma_f32_16x16x32_bf16((a), (b), (c), 0, 0, 0)

// load 8 consecutive elements as bf16x8 (fp32 source converted)
__device__ inline bf16x8 load8(const float* p) {
    const f32x4 a = *(const f32x4*)p;
    const f32x4 b = *(const f32x4*)(p + 4);
    bf16x8 r;
#pragma unroll
    for (int i = 0; i < 4; i++) { r[i] = (bf16_t)a[i]; r[4 + i] = (bf16_t)b[i]; }
    return r;
}
__device__ inline bf16x8 load8(const bf16_t* p) { return *(const bf16x8*)p; }

// 8-byte cross-lane shuffle of a packed bf16x4
__device__ inline bf16x4 shfl4(bf16x4 v, int src) {
    u64 x;
    __builtin_memcpy(&x, &v, 8);
    x = __shfl(x, src, 64);
    bf16x4 r;
    __builtin_memcpy(&r, &x, 8);
    return r;
}

// ---------------------------------------------------------------------------
// K/V swizzled layouts (MFMA-fragment order -> attn loads are base+lane*16):
//   k_sw: ((bh*128 + t>>4)*2 + (d>>5))*512 + ((t&15)+16*((d&31)>>3))*8 + (d&7)
//   v_sw: ((bh*64 + t>>5)*4 + (d>>4))*512 + ((d&15)+16*((t&31)>>3))*8 + (t&7)
// ---------------------------------------------------------------------------

// GEMM: C[M x N] = A[M x K] * B[N x K]^T, K=1024. Round-9 structure (proven):
// BMx128 tile, BK=32, 256 threads (4 waves), register staging, LDS stride 32.
// BM=128: wave = 64x64 (4x4 MFMA); BM=64: wave = 32x64 (2x4) -> 2x more blocks
// for small-N GEMMs (occupancy).
// MODE 0: store C row-major fp32 to outp (N = NDIM)
// MODE 1: qkv scatter epilogue WITH FUSED ROPE:
//   each wave covers one 64-wide head slot j = (n0+wn)>>6 (wave-uniform);
//   the rope pair (d, d+32) = (acc[im][in], acc[im][in+2]) lives in the same
//   lane -> rotation is per-lane fp32 register math + cos/sin table loads.
//   j<16 -> q_ws[bh][t][d] (scaled by 0.125*log2e); j<32 -> k_sw; else v_sw.
template <int MODE, int NDIM, int BM, typename TA>
__global__ __launch_bounds__(256) void gemm_bt(const TA* __restrict__ A,
                                               const float* __restrict__ B,
                                               float* __restrict__ outp,
                                               bf16_t* __restrict__ q_ws,
                                               bf16_t* __restrict__ k_ws,
                                               bf16_t* __restrict__ v_ws,
                                               const float* __restrict__ cosb,
                                               const float* __restrict__ sinb) {
    constexpr int K = 1024;
    constexpr int IM = BM / 32;  // m-subtiles per wave (4 or 2)
    __shared__ __align__(16) bf16_t As[BM * 32];
    __shared__ __align__(16) bf16_t Bs[128 * 32];

    const int tid = threadIdx.x;
    const int w = tid >> 6;
    const int lane = tid & 63;
    const int lr = lane & 15;
    const int quad = lane >> 4;
    const int m0 = blockIdx.y * BM;
    const int n0 = blockIdx.x * 128;
    const int wm = (w & 1) * (BM / 2);
    const int wn = (w >> 1) * 64;

    const int srow = tid >> 2;
    const int skk = (tid & 3) * 8;
    const TA* gA0 = A + (size_t)(m0 + srow) * K + skk;
    const TA* gA1 = gA0 + (size_t)64 * K;  // used only when BM==128
    const float* gB0 = B + (size_t)(n0 + srow) * K + skk;
    const float* gB1 = gB0 + (size_t)64 * K;

    f32x4 acc[IM][4] = {};

    for (int k0 = 0; k0 < K; k0 += 32) {
        const bf16x8 ra0 = load8(gA0 + k0);
        bf16x8 ra1;
        if constexpr (BM == 128) ra1 = load8(gA1 + k0);
        const bf16x8 rb0 = load8(gB0 + k0);
        const bf16x8 rb1 = load8(gB1 + k0);
        __syncthreads();  // previous iteration done reading LDS
        *(bf16x8*)&As[srow * 32 + skk] = ra0;
        if constexpr (BM == 128) *(bf16x8*)&As[(64 + srow) * 32 + skk] = ra1;
        *(bf16x8*)&Bs[srow * 32 + skk] = rb0;
        *(bf16x8*)&Bs[(64 + srow) * 32 + skk] = rb1;
        __syncthreads();  // LDS tile ready

        bf16x8 af[IM], bfm[4];
#pragma unroll
        for (int im = 0; im < IM; im++)
            af[im] = *(const bf16x8*)&As[(wm + im * 16 + lr) * 32 + quad * 8];
#pragma unroll
        for (int in = 0; in < 4; in++)
            bfm[in] = *(const bf16x8*)&Bs[(wn + in * 16 + lr) * 32 + quad * 8];
#pragma unroll
        for (int im = 0; im < IM; im++)
#pragma unroll
            for (int in = 0; in < 4; in++)
                acc[im][in] = MFMA16(af[im], bfm[in], acc[im][in]);
    }

    if constexpr (MODE == 0) {
#pragma unroll
        for (int im = 0; im < IM; im++)
#pragma unroll
            for (int in = 0; in < 4; in++)
#pragma unroll
                for (int r = 0; r < 4; r++) {
                    const int m = m0 + wm + im * 16 + quad * 4 + r;
                    const int n = n0 + wn + in * 16 + lr;
                    outp[(size_t)m * NDIM + n] = acc[im][in][r];
                }
    } else {
        const int j = (n0 + wn) >> 6;  // wave-uniform head slot (48 total)
        if (j < 32) {
            // q or k: fused RoPE on fp32 accumulators
            const bool isq = (j < 16);
            const float qs = 0.125f * 1.44269504089f;  // attn uses exp2
#pragma unroll
            for (int im = 0; im < IM; im++) {
#pragma unroll
                for (int r = 0; r < 4; r++) {
                    const int m = m0 + wm + im * 16 + quad * 4 + r;
                    const int b = m >> 11;  // T = 2048
                    const int t = m & 2047;
#pragma unroll
                    for (int in = 0; in < 2; in++) {
                        const int d = in * 16 + lr;  // [0,32)
                        const float x1 = acc[im][in][r];
                        const float x2 = acc[im][in + 2][r];
                        const float c = cosb[t * 64 + d];
                        const float s = sinb[t * 64 + d];
                        float y1 = x1 * c - x2 * s;
                        float y2 = x2 * c + x1 * s;
                        if (isq) {
                            y1 *= qs; y2 *= qs;
                            const size_t base =
                                ((size_t)(b * 16 + j) * 2048 + t) * 64 + d;
                            q_ws[base] = (bf16_t)y1;
                            q_ws[base + 32] = (bf16_t)y2;
                        } else {
                            const int bh = b * 16 + (j - 16);
                            const size_t off =
                                ((size_t)(bh * 128 + (t >> 4)) * 2) * 512 +
                                ((t & 15) + (d >> 3) * 16) * 8 + (d & 7);
                            k_ws[off] = (bf16_t)y1;
                            k_ws[off + 512] = (bf16_t)y2;
                        }
                    }
                }
            }
        } else {
            // v: plain swizzled scatter
#pragma unroll
            for (int im = 0; im < IM; im++)
#pragma unroll
                for (int in = 0; in < 4; in++)
#pragma unroll
                    for (int r = 0; r < 4; r++) {
                        const int m = m0 + wm + im * 16 + quad * 4 + r;
                        const int b = m >> 11;
                        const int t = m & 2047;
                        const int d = in * 16 + lr;
                        const int bh = b * 16 + (j - 32);
                        const size_t off =
                            ((size_t)(bh * 64 + (t >> 5)) * 4 + (d >> 4)) * 512 +
                            ((d & 15) + ((t & 31) >> 3) * 16) * 8 + (t & 7);
                        v_ws[off] = (bf16_t)acc[im][in][r];
                    }
        }
    }
}

// ---------------------------------------------------------------------------
// Flash attention: transposed-score, barrier/LDS/max-free, coalesced swizzled
// K/V loads (1KB contiguous per instruction) + register double-buffer K
// prefetch across the back-edge (V issued at body top, consumed at bottom).
// Grid: blockIdx.x = qt'*32 + bh, qt = 31-qt' (LPT). 4 independent waves;
// wave w owns queries [qt*64+16w, +16).
// ---------------------------------------------------------------------------
__global__ __launch_bounds__(256) void attn_kernel(const bf16_t* __restrict__ q_ws,
                                                   const bf16_t* __restrict__ k_ws,
                                                   const bf16_t* __restrict__ v_ws,
                                                   bf16_t* __restrict__ ctx) {
    const int tid = threadIdx.x;
    const int w = tid >> 6;
    const int lane = tid & 63;
    const int lr = lane & 15;
    const int quad = lane >> 4;
    const int bh = blockIdx.x & 31;
    const int qt = 31 - (blockIdx.x >> 5);  // LPT
    const int trow = qt * 64 + w * 16;
    const int query = trow + lr;

    const bf16_t* qb = q_ws + ((size_t)bh * 2048 + trow + lr) * 64 + quad * 8;
    const bf16x8 qlo = *(const bf16x8*)qb;
    const bf16x8 qhi = *(const bf16x8*)(qb + 32);

    const bf16_t* kbase = k_ws + (size_t)bh * 131072 + lane * 8;
    const bf16_t* vbase = v_ws + (size_t)bh * 131072 + lane * 8;

    f32x4 o[4] = {};
    float lrun = 0.0f;

    const int srcLow = ((quad & 1) << 5) + lr;
    const int srcHigh = srcLow + 16;
    const bool loSel = (quad < 2);

    // K chunk address: ((kb*4+n)*2 + half)*512 ; V: ((kb*2+hh)*4 + n)*512
    bf16x8 kc[8];
#pragma unroll
    for (int n = 0; n < 4; n++) {
        kc[2 * n] = *(const bf16x8*)(kbase + (size_t)(n * 2) * 512);
        kc[2 * n + 1] = *(const bf16x8*)(kbase + (size_t)(n * 2 + 1) * 512);
    }

    for (int kb = 0; kb <= qt; kb++) {
        // V(kb) loads: consumed at body end -> full-body latency cover
        bf16x8 vv[2][4];
#pragma unroll
        for (int hh = 0; hh < 2; hh++)
#pragma unroll
            for (int n = 0; n < 4; n++)
                vv[hh][n] = *(const bf16x8*)(vbase +
                    (size_t)((kb * 2 + hh) * 4 + n) * 512);

        // K(kb+1) prefetch (uniform; last iter harmlessly reloads qt)
        const int kbn = (kb < qt) ? kb + 1 : kb;
        bf16x8 kn[8];
#pragma unroll
        for (int n = 0; n < 4; n++) {
            kn[2 * n] = *(const bf16x8*)(kbase + (size_t)((kbn * 4 + n) * 2) * 512);
            kn[2 * n + 1] = *(const bf16x8*)(kbase + (size_t)((kbn * 4 + n) * 2 + 1) * 512);
        }

        const int u0 = kb * 64;
        f32x4 s[4];
#pragma unroll
        for (int n = 0; n < 4; n++) {
            const f32x4 z = {};
            s[n] = MFMA16(kc[2 * n], qlo, z);
            s[n] = MFMA16(kc[2 * n + 1], qhi, s[n]);
        }

        if (kb == qt) {  // diagonal 64-key block: causal mask (key > query)
#pragma unroll
            for (int n = 0; n < 4; n++)
#pragma unroll
                for (int r = 0; r < 4; r++)
                    if (u0 + n * 16 + quad * 4 + r > query) s[n][r] = -1e9f;
        }

        f32x4 p[4];
#pragma unroll
        for (int n = 0; n < 4; n++)
#pragma unroll
            for (int r = 0; r < 4; r++) p[n][r] = exp2f(s[n][r]);

        lrun += ((p[0][0] + p[0][1]) + (p[0][2] + p[0][3])) +
                ((p[1][0] + p[1][1]) + (p[1][2] + p[1][3])) +
                ((p[2][0] + p[2][1]) + (p[2][2] + p[2][3])) +
                ((p[3][0] + p[3][1]) + (p[3][2] + p[3][3]));

        bf16x4 pb[4];
#pragma unroll
        for (int n = 0; n < 4; n++)
#pragma unroll
            for (int r = 0; r < 4; r++) pb[n][r] = (bf16_t)p[n][r];

#pragma unroll
        for (int hh = 0; hh < 2; hh++) {  // 32-key halves
            const bf16x4 a0 = shfl4(pb[2 * hh], srcLow);
            const bf16x4 a1 = shfl4(pb[2 * hh + 1], srcLow);
            const bf16x4 b0 = shfl4(pb[2 * hh], srcHigh);
            const bf16x4 b1 = shfl4(pb[2 * hh + 1], srcHigh);
            const bf16x4 lo = loSel ? a0 : a1;
            const bf16x4 hi = loSel ? b0 : b1;
            bf16x8 pf;
#pragma unroll
            for (int r = 0; r < 4; r++) { pf[r] = lo[r]; pf[4 + r] = hi[r]; }

#pragma unroll
            for (int n = 0; n < 4; n++)
                o[n] = MFMA16(vv[hh][n], pf, o[n]);
        }

#pragma unroll
        for (int i = 0; i < 8; i++) kc[i] = kn[i];
    }

    // final l reduction across the 4 quads holding this query's keys
    lrun += __shfl_xor(lrun, 16);
    lrun += __shfl_xor(lrun, 32);

    // epilogue: lane owns query=trow+lr, d = n*16 + quad*4 + r
    const int b = bh >> 4;
    const int hd = bh & 15;
    const float inv = 1.0f / fmaxf(lrun, 1e-30f);
    const size_t base = ((size_t)b * 2048 + query) * 1024 + hd * 64 + quad * 4;
#pragma unroll
    for (int n = 0; n < 4; n++) {
        bf16x4 ob;
#pragma unroll
        for (int r = 0; r < 4; r++) ob[r] = (bf16_t)(o[n][r] * inv);
        *(bf16x4*)&ctx[base + n * 16] = ob;
    }
}

// ---------------------------------------------------------------------------
// Launcher. Inputs fp32, output fp32. ws: q_ws[0,8M) k_sw[8M,16M) v_sw[16M,24M)
// ctx[24M,32M)
// ---------------------------------------------------------------------------
extern "C" void kernel_launch(void* const* d_in, const int* in_sizes, int n_in,
                              void* d_out, int out_size, void* d_ws, size_t ws_size,
                              hipStream_t stream) {
    const float* hs = (const float*)d_in[0];
    const float* cosb = (const float*)d_in[1];
    const float* sinb = (const float*)d_in[2];
    const float* wqkv = (const float*)d_in[3];
    const float* wo = (const float*)d_in[4];
    float* out = (float*)d_out;

    char* ws = (char*)d_ws;
    bf16_t* q_ws = (bf16_t*)(ws);
    bf16_t* k_ws = (bf16_t*)(ws + (size_t)(8u << 20));
    bf16_t* v_ws = (bf16_t*)(ws + (size_t)(16u << 20));
    bf16_t* ctx = (bf16_t*)(ws + (size_t)(24u << 20));

    const dim3 blk(256);

    // 1) QKV projection + fused RoPE + scatter: M=4096, N=3072, K=1024
    gemm_bt<1, 3072, 128><<<dim3(24, 32), blk, 0, stream>>>(
        hs, wqkv, nullptr, q_ws, k_ws, v_ws, cosb, sinb);

    // 2) Flash attention -> ctx [B,T,1024] (bf16)
    attn_kernel<<<dim3(1024), blk, 0, stream>>>(q_ws, k_ws, v_ws, ctx);

    // 3) Output projection: M=4096, N=1024, K=1024 (A = ctx bf16, BM=64 ->
    //    512 blocks = 2/CU for latency hiding)
    gemm_bt<0, 1024, 64><<<dim3(8, 64), blk, 0, stream>>>(
        ctx, wo, out, nullptr, nullptr, nullptr, nullptr, nullptr);
}

// Round 12
// 181.076 us; speedup vs baseline: 1.3821x; 1.1058x over previous
//
#include <hip/hip_runtime.h>

typedef __bf16 bf16_t;
typedef __bf16 bf16x4 __attribute__((ext_vector_type(4)));
typedef __bf16 bf16x8 __attribute__((ext_vector_type(8)));
typedef float f32x4 __attribute__((ext_vector_type(4)));
typedef unsigned long long u64;

#define MFMA16(a, b, c) __builtin_amdgcn_mfma_f32_16x16x32_bf16((a), (b), (c), 0, 0, 0)

#define LDG2LDS16(g, l)                                                        \
    __builtin_amdgcn_global_load_lds(                                          \
        (const __attribute__((address_space(1))) void*)(g),                    \
        (__attribute__((address_space(3))) void*)(l), 16, 0, 0)

// load 8 consecutive fp32 as bf16x8
__device__ inline bf16x8 load8(const float* p) {
    const f32x4 a = *(const f32x4*)p;
    const f32x4 b = *(const f32x4*)(p + 4);
    bf16x8 r;
#pragma unroll
    for (int i = 0; i < 4; i++) { r[i] = (bf16_t)a[i]; r[4 + i] = (bf16_t)b[i]; }
    return r;
}

// 8-byte cross-lane shuffle of a packed bf16x4
__device__ inline bf16x4 shfl4(bf16x4 v, int src) {
    u64 x;
    __builtin_memcpy(&x, &v, 8);
    x = __shfl(x, src, 64);
    bf16x4 r;
    __builtin_memcpy(&r, &x, 8);
    return r;
}

// ---------------------------------------------------------------------------
// fp32 -> bf16 convert: hs (4194304 el) | wqkv (3145728 el) | wo (1048576 el)
// packed contiguously into `outb` (elem bases 0 / 4194304 / 7340032).
// 8 elems/thread, 4096 blocks x 256.
// ---------------------------------------------------------------------------
__global__ __launch_bounds__(256) void convert_kernel(const float* __restrict__ hs,
                                                      const float* __restrict__ wqkv,
                                                      const float* __restrict__ wo,
                                                      bf16_t* __restrict__ outb) {
    const size_t c = ((size_t)blockIdx.x * 256 + threadIdx.x) * 8;
    const float* src;
    size_t off;
    if (c < 4194304) { src = hs; off = c; }
    else if (c < 7340032) { src = wqkv; off = c - 4194304; }
    else { src = wo; off = c - 7340032; }
    *(bf16x8*)(outb + c) = load8(src + off);
}

// ---------------------------------------------------------------------------
// K/V swizzled layouts (MFMA-fragment order -> attn loads are base+lane*16):
//   k_sw: ((bh*128 + t>>4)*2 + (d>>5))*512 + ((t&15)+16*((d&31)>>3))*8 + (d&7)
//   v_sw: ((bh*64 + t>>5)*4 + (d>>4))*512 + ((d&15)+16*((t&31)>>3))*8 + (t&7)
// ---------------------------------------------------------------------------

// GEMM: C[M x N] = A[M x K] * B[N x K]^T, K=1024, bf16 in (pre-converted).
// m97 structure: BMx128 tile, BK=32, 256 threads (4 waves),
// global_load_lds width-16 staging (HBM->LDS DMA, no VGPR round-trip),
// 2-barrier K-loop. Staging map: thread tid -> LDS elem tid*8 (row tid>>2,
// k-chunk (tid&3)*8); DMA dest = wave-uniform base + lane*16B.
// MODE 0: store C row-major fp32 to outp (N = NDIM)
// MODE 1: qkv scatter epilogue with fused RoPE (wave-uniform head slot j):
//   j<16 -> q_ws[bh][t][d] (scaled 0.125*log2e); j<32 -> k_sw; else v_sw
template <int MODE, int NDIM, int BM>
__global__ __launch_bounds__(256) void gemm_bt(const bf16_t* __restrict__ A,
                                               const bf16_t* __restrict__ B,
                                               float* __restrict__ outp,
                                               bf16_t* __restrict__ q_ws,
                                               bf16_t* __restrict__ k_ws,
                                               bf16_t* __restrict__ v_ws,
                                               const float* __restrict__ cosb,
                                               const float* __restrict__ sinb) {
    constexpr int K = 1024;
    constexpr int IM = BM / 32;  // m-subtiles per wave (4 or 2)
    __shared__ __align__(16) bf16_t As[BM * 32];
    __shared__ __align__(16) bf16_t Bs[128 * 32];

    const int tid = threadIdx.x;
    const int w = tid >> 6;
    const int lane = tid & 63;
    const int lr = lane & 15;
    const int quad = lane >> 4;
    const int m0 = blockIdx.y * BM;
    const int n0 = blockIdx.x * 128;
    const int wm = (w & 1) * (BM / 2);
    const int wn = (w >> 1) * 64;

    const int srow = tid >> 2;
    const int skk = (tid & 3) * 8;
    const bf16_t* gA0 = A + (size_t)(m0 + srow) * K + skk;
    const bf16_t* gA1 = gA0 + (size_t)64 * K;  // only when BM==128
    const bf16_t* gB0 = B + (size_t)(n0 + srow) * K + skk;
    const bf16_t* gB1 = gB0 + (size_t)64 * K;
    // wave-uniform LDS DMA bases (thread tid lands at base + lane*16B)
    bf16_t* lA0 = As + w * 512;
    bf16_t* lA1 = As + 2048 + w * 512;
    bf16_t* lB0 = Bs + w * 512;
    bf16_t* lB1 = Bs + 2048 + w * 512;

    f32x4 acc[IM][4] = {};

    for (int k0 = 0; k0 < K; k0 += 32) {
        LDG2LDS16(gA0 + k0, lA0);
        if constexpr (BM == 128) LDG2LDS16(gA1 + k0, lA1);
        LDG2LDS16(gB0 + k0, lB0);
        LDG2LDS16(gB1 + k0, lB1);
        __syncthreads();  // DMA drained (implicit vmcnt(0)), tile ready

        bf16x8 af[IM], bfm[4];
#pragma unroll
        for (int im = 0; im < IM; im++)
            af[im] = *(const bf16x8*)&As[(wm + im * 16 + lr) * 32 + quad * 8];
#pragma unroll
        for (int in = 0; in < 4; in++)
            bfm[in] = *(const bf16x8*)&Bs[(wn + in * 16 + lr) * 32 + quad * 8];
#pragma unroll
        for (int im = 0; im < IM; im++)
#pragma unroll
            for (int in = 0; in < 4; in++)
                acc[im][in] = MFMA16(af[im], bfm[in], acc[im][in]);
        __syncthreads();  // all waves done reading before next DMA overwrites
    }

    if constexpr (MODE == 0) {
#pragma unroll
        for (int im = 0; im < IM; im++)
#pragma unroll
            for (int in = 0; in < 4; in++)
#pragma unroll
                for (int r = 0; r < 4; r++) {
                    const int m = m0 + wm + im * 16 + quad * 4 + r;
                    const int n = n0 + wn + in * 16 + lr;
                    outp[(size_t)m * NDIM + n] = acc[im][in][r];
                }
    } else {
        const int j = (n0 + wn) >> 6;  // wave-uniform head slot (48 total)
        if (j < 32) {
            // q or k: fused RoPE on fp32 accumulators
            const bool isq = (j < 16);
            const float qs = 0.125f * 1.44269504089f;  // attn uses exp2
#pragma unroll
            for (int im = 0; im < IM; im++) {
#pragma unroll
                for (int r = 0; r < 4; r++) {
                    const int m = m0 + wm + im * 16 + quad * 4 + r;
                    const int b = m >> 11;  // T = 2048
                    const int t = m & 2047;
#pragma unroll
                    for (int in = 0; in < 2; in++) {
                        const int d = in * 16 + lr;  // [0,32)
                        const float x1 = acc[im][in][r];
                        const float x2 = acc[im][in + 2][r];
                        const float c = cosb[t * 64 + d];
                        const float s = sinb[t * 64 + d];
                        float y1 = x1 * c - x2 * s;
                        float y2 = x2 * c + x1 * s;
                        if (isq) {
                            y1 *= qs; y2 *= qs;
                            const size_t base =
                                ((size_t)(b * 16 + j) * 2048 + t) * 64 + d;
                            q_ws[base] = (bf16_t)y1;
                            q_ws[base + 32] = (bf16_t)y2;
                        } else {
                            const int bh = b * 16 + (j - 16);
                            const size_t off =
                                ((size_t)(bh * 128 + (t >> 4)) * 2) * 512 +
                                ((t & 15) + (d >> 3) * 16) * 8 + (d & 7);
                            k_ws[off] = (bf16_t)y1;
                            k_ws[off + 512] = (bf16_t)y2;
                        }
                    }
                }
            }
        } else {
            // v: plain swizzled scatter
#pragma unroll
            for (int im = 0; im < IM; im++)
#pragma unroll
                for (int in = 0; in < 4; in++)
#pragma unroll
                    for (int r = 0; r < 4; r++) {
                        const int m = m0 + wm + im * 16 + quad * 4 + r;
                        const int b = m >> 11;
                        const int t = m & 2047;
                        const int d = in * 16 + lr;
                        const int bh = b * 16 + (j - 32);
                        const size_t off =
                            ((size_t)(bh * 64 + (t >> 5)) * 4 + (d >> 4)) * 512 +
                            ((d & 15) + ((t & 31) >> 3) * 16) * 8 + (t & 7);
                        v_ws[off] = (bf16_t)acc[im][in][r];
                    }
        }
    }
}

// ---------------------------------------------------------------------------
// Flash attention: transposed-score, barrier/LDS/max-free, coalesced swizzled
// K/V loads (1KB contiguous per instruction) + register double-buffer K
// prefetch across the back-edge (V issued at body top, consumed at bottom).
// Grid: blockIdx.x = qt'*32 + bh, qt = 31-qt' (LPT). 4 independent waves;
// wave w owns queries [qt*64+16w, +16).
// ---------------------------------------------------------------------------
__global__ __launch_bounds__(256) void attn_kernel(const bf16_t* __restrict__ q_ws,
                                                   const bf16_t* __restrict__ k_ws,
                                                   const bf16_t* __restrict__ v_ws,
                                                   bf16_t* __restrict__ ctx) {
    const int tid = threadIdx.x;
    const int w = tid >> 6;
    const int lane = tid & 63;
    const int lr = lane & 15;
    const int quad = lane >> 4;
    const int bh = blockIdx.x & 31;
    const int qt = 31 - (blockIdx.x >> 5);  // LPT
    const int trow = qt * 64 + w * 16;
    const int query = trow + lr;

    const bf16_t* qb = q_ws + ((size_t)bh * 2048 + trow + lr) * 64 + quad * 8;
    const bf16x8 qlo = *(const bf16x8*)qb;
    const bf16x8 qhi = *(const bf16x8*)(qb + 32);

    const bf16_t* kbase = k_ws + (size_t)bh * 131072 + lane * 8;
    const bf16_t* vbase = v_ws + (size_t)bh * 131072 + lane * 8;

    f32x4 o[4] = {};
    float lrun = 0.0f;

    const int srcLow = ((quad & 1) << 5) + lr;
    const int srcHigh = srcLow + 16;
    const bool loSel = (quad < 2);

    // K chunk address: ((kb*4+n)*2 + half)*512 ; V: ((kb*2+hh)*4 + n)*512
    bf16x8 kc[8];
#pragma unroll
    for (int n = 0; n < 4; n++) {
        kc[2 * n] = *(const bf16x8*)(kbase + (size_t)(n * 2) * 512);
        kc[2 * n + 1] = *(const bf16x8*)(kbase + (size_t)(n * 2 + 1) * 512);
    }

    for (int kb = 0; kb <= qt; kb++) {
        // V(kb) loads: consumed at body end -> full-body latency cover
        bf16x8 vv[2][4];
#pragma unroll
        for (int hh = 0; hh < 2; hh++)
#pragma unroll
            for (int n = 0; n < 4; n++)
                vv[hh][n] = *(const bf16x8*)(vbase +
                    (size_t)((kb * 2 + hh) * 4 + n) * 512);

        // K(kb+1) prefetch (uniform; last iter harmlessly reloads qt)
        const int kbn = (kb < qt) ? kb + 1 : kb;
        bf16x8 kn[8];
#pragma unroll
        for (int n = 0; n < 4; n++) {
            kn[2 * n] = *(const bf16x8*)(kbase + (size_t)((kbn * 4 + n) * 2) * 512);
            kn[2 * n + 1] = *(const bf16x8*)(kbase + (size_t)((kbn * 4 + n) * 2 + 1) * 512);
        }

        const int u0 = kb * 64;
        f32x4 s[4];
#pragma unroll
        for (int n = 0; n < 4; n++) {
            const f32x4 z = {};
            s[n] = MFMA16(kc[2 * n], qlo, z);
            s[n] = MFMA16(kc[2 * n + 1], qhi, s[n]);
        }

        if (kb == qt) {  // diagonal 64-key block: causal mask (key > query)
#pragma unroll
            for (int n = 0; n < 4; n++)
#pragma unroll
                for (int r = 0; r < 4; r++)
                    if (u0 + n * 16 + quad * 4 + r > query) s[n][r] = -1e9f;
        }

        f32x4 p[4];
#pragma unroll
        for (int n = 0; n < 4; n++)
#pragma unroll
            for (int r = 0; r < 4; r++) p[n][r] = exp2f(s[n][r]);

        lrun += ((p[0][0] + p[0][1]) + (p[0][2] + p[0][3])) +
                ((p[1][0] + p[1][1]) + (p[1][2] + p[1][3])) +
                ((p[2][0] + p[2][1]) + (p[2][2] + p[2][3])) +
                ((p[3][0] + p[3][1]) + (p[3][2] + p[3][3]));

        bf16x4 pb[4];
#pragma unroll
        for (int n = 0; n < 4; n++)
#pragma unroll
            for (int r = 0; r < 4; r++) pb[n][r] = (bf16_t)p[n][r];

#pragma unroll
        for (int hh = 0; hh < 2; hh++) {  // 32-key halves
            const bf16x4 a0 = shfl4(pb[2 * hh], srcLow);
            const bf16x4 a1 = shfl4(pb[2 * hh + 1], srcLow);
            const bf16x4 b0 = shfl4(pb[2 * hh], srcHigh);
            const bf16x4 b1 = shfl4(pb[2 * hh + 1], srcHigh);
            const bf16x4 lo = loSel ? a0 : a1;
            const bf16x4 hi = loSel ? b0 : b1;
            bf16x8 pf;
#pragma unroll
            for (int r = 0; r < 4; r++) { pf[r] = lo[r]; pf[4 + r] = hi[r]; }

#pragma unroll
            for (int n = 0; n < 4; n++)
                o[n] = MFMA16(vv[hh][n], pf, o[n]);
        }

#pragma unroll
        for (int i = 0; i < 8; i++) kc[i] = kn[i];
    }

    // final l reduction across the 4 quads holding this query's keys
    lrun += __shfl_xor(lrun, 16);
    lrun += __shfl_xor(lrun, 32);

    // epilogue: lane owns query=trow+lr, d = n*16 + quad*4 + r
    const int b = bh >> 4;
    const int hd = bh & 15;
    const float inv = 1.0f / fmaxf(lrun, 1e-30f);
    const size_t base = ((size_t)b * 2048 + query) * 1024 + hd * 64 + quad * 4;
#pragma unroll
    for (int n = 0; n < 4; n++) {
        bf16x4 ob;
#pragma unroll
        for (int r = 0; r < 4; r++) ob[r] = (bf16_t)(o[n][r] * inv);
        *(bf16x4*)&ctx[base + n * 16] = ob;
    }
}

// ---------------------------------------------------------------------------
// Launcher. Inputs fp32, output fp32.
// ws bytes: [0,8M) hs_b -> (after gemm1) ctx overlay | [8M,14M) wqkv_b |
//           [14M,16M) wo_b | [16M,24M) q | [24M,32M) k | [32M,40M) v.
// Peak 40 MB. Overlay safe: attn writes ctx strictly after gemm1 reads hs_b.
// ---------------------------------------------------------------------------
extern "C" void kernel_launch(void* const* d_in, const int* in_sizes, int n_in,
                              void* d_out, int out_size, void* d_ws, size_t ws_size,
                              hipStream_t stream) {
    const float* hs = (const float*)d_in[0];
    const float* cosb = (const float*)d_in[1];
    const float* sinb = (const float*)d_in[2];
    const float* wqkv = (const float*)d_in[3];
    const float* wo = (const float*)d_in[4];
    float* out = (float*)d_out;

    char* ws = (char*)d_ws;
    bf16_t* hs_b = (bf16_t*)(ws);                              // 4194304 el
    bf16_t* wqkv_b = hs_b + 4194304;                           // 3145728 el
    bf16_t* wo_b = hs_b + 7340032;                             // 1048576 el
    bf16_t* q_ws = (bf16_t*)(ws + (size_t)(16u << 20));
    bf16_t* k_ws = (bf16_t*)(ws + (size_t)(24u << 20));
    bf16_t* v_ws = (bf16_t*)(ws + (size_t)(32u << 20));
    bf16_t* ctx = (bf16_t*)(ws);  // overlays hs_b (dead after gemm1)

    const dim3 blk(256);

    // 0) fp32 -> bf16 convert (hs | wqkv | wo packed)
    convert_kernel<<<dim3(4096), blk, 0, stream>>>(hs, wqkv, wo, hs_b);

    // 1) QKV projection + fused RoPE + scatter: M=4096, N=3072, K=1024
    gemm_bt<1, 3072, 128><<<dim3(24, 32), blk, 0, stream>>>(
        hs_b, wqkv_b, nullptr, q_ws, k_ws, v_ws, cosb, sinb);

    // 2) Flash attention -> ctx [B,T,1024] (bf16, overlays hs_b)
    attn_kernel<<<dim3(1024), blk, 0, stream>>>(q_ws, k_ws, v_ws, ctx);

    // 3) Output projection: M=4096, N=1024, K=1024 (BM=64 -> 512 blocks)
    gemm_bt<0, 1024, 64><<<dim3(8, 64), blk, 0, stream>>>(
        ctx, wo_b, out, nullptr, nullptr, nullptr, nullptr, nullptr);
}

// Round 13
// 177.993 us; speedup vs baseline: 1.4061x; 1.0173x over previous
//
#include <hip/hip_runtime.h>

typedef __bf16 bf16_t;
typedef __bf16 bf16x4 __attribute__((ext_vector_type(4)));
typedef __bf16 bf16x8 __attribute__((ext_vector_type(8)));
typedef float f32x4 __attribute__((ext_vector_type(4)));
typedef unsigned int u32x2 __attribute__((ext_vector_type(2)));
typedef unsigned long long u64;

#define MFMA16(a, b, c) __builtin_amdgcn_mfma_f32_16x16x32_bf16((a), (b), (c), 0, 0, 0)

#define LDG2LDS16(g, l)                                                        \
    __builtin_amdgcn_global_load_lds(                                          \
        (const __attribute__((address_space(1))) void*)(g),                    \
        (__attribute__((address_space(3))) void*)(l), 16, 0, 0)

#if __has_builtin(__builtin_amdgcn_exp2f)
#define EXP2(x) __builtin_amdgcn_exp2f(x)
#else
#define EXP2(x) exp2f(x)
#endif

// load 8 consecutive fp32 as bf16x8
__device__ inline bf16x8 load8(const float* p) {
    const f32x4 a = *(const f32x4*)p;
    const f32x4 b = *(const f32x4*)(p + 4);
    bf16x8 r;
#pragma unroll
    for (int i = 0; i < 4; i++) { r[i] = (bf16_t)a[i]; r[4 + i] = (bf16_t)b[i]; }
    return r;
}

__device__ inline u32x2 as2(bf16x4 v) {
    u32x2 r;
    __builtin_memcpy(&r, &v, 8);
    return r;
}

// 8-byte cross-lane shuffle of a packed bf16x4 (fallback path)
__device__ inline bf16x4 shfl4(bf16x4 v, int src) {
    u64 x;
    __builtin_memcpy(&x, &v, 8);
    x = __shfl(x, src, 64);
    bf16x4 r;
    __builtin_memcpy(&r, &x, 8);
    return r;
}

// ---------------------------------------------------------------------------
// fp32 -> bf16 convert: hs (4194304 el) | wqkv (3145728 el) | wo (1048576 el)
// ---------------------------------------------------------------------------
__global__ __launch_bounds__(256) void convert_kernel(const float* __restrict__ hs,
                                                      const float* __restrict__ wqkv,
                                                      const float* __restrict__ wo,
                                                      bf16_t* __restrict__ outb) {
    const size_t c = ((size_t)blockIdx.x * 256 + threadIdx.x) * 8;
    const float* src;
    size_t off;
    if (c < 4194304) { src = hs; off = c; }
    else if (c < 7340032) { src = wqkv; off = c - 4194304; }
    else { src = wo; off = c - 7340032; }
    *(bf16x8*)(outb + c) = load8(src + off);
}

// ---------------------------------------------------------------------------
// K/V swizzled layouts (MFMA-fragment order -> attn loads are base+lane*16):
//   k_sw: ((bh*128 + t>>4)*2 + (d>>5))*512 + ((t&15)+16*((d&31)>>3))*8 + (d&7)
//   v_sw: ((bh*64 + t>>5)*4 + (d>>4))*512 + ((d&15)+16*((t&31)>>3))*8 + (t&7)
// ---------------------------------------------------------------------------

// GEMM (m97 structure, unchanged from round 12).
template <int MODE, int NDIM, int BM>
__global__ __launch_bounds__(256) void gemm_bt(const bf16_t* __restrict__ A,
                                               const bf16_t* __restrict__ B,
                                               float* __restrict__ outp,
                                               bf16_t* __restrict__ q_ws,
                                               bf16_t* __restrict__ k_ws,
                                               bf16_t* __restrict__ v_ws,
                                               const float* __restrict__ cosb,
                                               const float* __restrict__ sinb) {
    constexpr int K = 1024;
    constexpr int IM = BM / 32;
    __shared__ __align__(16) bf16_t As[BM * 32];
    __shared__ __align__(16) bf16_t Bs[128 * 32];

    const int tid = threadIdx.x;
    const int w = tid >> 6;
    const int lane = tid & 63;
    const int lr = lane & 15;
    const int quad = lane >> 4;
    const int m0 = blockIdx.y * BM;
    const int n0 = blockIdx.x * 128;
    const int wm = (w & 1) * (BM / 2);
    const int wn = (w >> 1) * 64;

    const int srow = tid >> 2;
    const int skk = (tid & 3) * 8;
    const bf16_t* gA0 = A + (size_t)(m0 + srow) * K + skk;
    const bf16_t* gA1 = gA0 + (size_t)64 * K;
    const bf16_t* gB0 = B + (size_t)(n0 + srow) * K + skk;
    const bf16_t* gB1 = gB0 + (size_t)64 * K;
    bf16_t* lA0 = As + w * 512;
    bf16_t* lA1 = As + 2048 + w * 512;
    bf16_t* lB0 = Bs + w * 512;
    bf16_t* lB1 = Bs + 2048 + w * 512;

    f32x4 acc[IM][4] = {};

    for (int k0 = 0; k0 < K; k0 += 32) {
        LDG2LDS16(gA0 + k0, lA0);
        if constexpr (BM == 128) LDG2LDS16(gA1 + k0, lA1);
        LDG2LDS16(gB0 + k0, lB0);
        LDG2LDS16(gB1 + k0, lB1);
        __syncthreads();

        bf16x8 af[IM], bfm[4];
#pragma unroll
        for (int im = 0; im < IM; im++)
            af[im] = *(const bf16x8*)&As[(wm + im * 16 + lr) * 32 + quad * 8];
#pragma unroll
        for (int in = 0; in < 4; in++)
            bfm[in] = *(const bf16x8*)&Bs[(wn + in * 16 + lr) * 32 + quad * 8];
#pragma unroll
        for (int im = 0; im < IM; im++)
#pragma unroll
            for (int in = 0; in < 4; in++)
                acc[im][in] = MFMA16(af[im], bfm[in], acc[im][in]);
        __syncthreads();
    }

    if constexpr (MODE == 0) {
#pragma unroll
        for (int im = 0; im < IM; im++)
#pragma unroll
            for (int in = 0; in < 4; in++)
#pragma unroll
                for (int r = 0; r < 4; r++) {
                    const int m = m0 + wm + im * 16 + quad * 4 + r;
                    const int n = n0 + wn + in * 16 + lr;
                    outp[(size_t)m * NDIM + n] = acc[im][in][r];
                }
    } else {
        const int j = (n0 + wn) >> 6;
        if (j < 32) {
            const bool isq = (j < 16);
            const float qs = 0.125f * 1.44269504089f;
#pragma unroll
            for (int im = 0; im < IM; im++) {
#pragma unroll
                for (int r = 0; r < 4; r++) {
                    const int m = m0 + wm + im * 16 + quad * 4 + r;
                    const int b = m >> 11;
                    const int t = m & 2047;
#pragma unroll
                    for (int in = 0; in < 2; in++) {
                        const int d = in * 16 + lr;
                        const float x1 = acc[im][in][r];
                        const float x2 = acc[im][in + 2][r];
                        const float c = cosb[t * 64 + d];
                        const float s = sinb[t * 64 + d];
                        float y1 = x1 * c - x2 * s;
                        float y2 = x2 * c + x1 * s;
                        if (isq) {
                            y1 *= qs; y2 *= qs;
                            const size_t base =
                                ((size_t)(b * 16 + j) * 2048 + t) * 64 + d;
                            q_ws[base] = (bf16_t)y1;
                            q_ws[base + 32] = (bf16_t)y2;
                        } else {
                            const int bh = b * 16 + (j - 16);
                            const size_t off =
                                ((size_t)(bh * 128 + (t >> 4)) * 2) * 512 +
                                ((t & 15) + (d >> 3) * 16) * 8 + (d & 7);
                            k_ws[off] = (bf16_t)y1;
                            k_ws[off + 512] = (bf16_t)y2;
                        }
                    }
                }
            }
        } else {
#pragma unroll
            for (int im = 0; im < IM; im++)
#pragma unroll
                for (int in = 0; in < 4; in++)
#pragma unroll
                    for (int r = 0; r < 4; r++) {
                        const int m = m0 + wm + im * 16 + quad * 4 + r;
                        const int b = m >> 11;
                        const int t = m & 2047;
                        const int d = in * 16 + lr;
                        const int bh = b * 16 + (j - 32);
                        const size_t off =
                            ((size_t)(bh * 64 + (t >> 5)) * 4 + (d >> 4)) * 512 +
                            ((d & 15) + ((t & 31) >> 3) * 16) * 8 + (t & 7);
                        v_ws[off] = (bf16_t)acc[im][in][r];
                    }
        }
    }
}

// ---------------------------------------------------------------------------
// One flash tile: 16 queries (this wave), keys 0..(qt+1)*64. Transposed-score,
// max-free, LDS-free. P C-layout -> PV B-fragment via 6 permlane-swaps per
// 32-key half (gfx950 v_permlane16/32_swap; verified algebra:
//   stage1 p16s(x,y)->(x0,y0,x2,y2),(x1,y1,x3,y3) per reg;
//   stage2 p32s pairs A/B regs; stage3 p16s -> pf dwords
//   (x0,x2,x0',x2') (y0,y2,y0',y2') (x1,x3,x1',x3') (y1,y3,y1',y3') ),
// falling back to ds_bpermute shuffles if the builtin is missing.
// ---------------------------------------------------------------------------
__device__ inline void flash_tile(int qt, int quad, int lr, int query,
                                  const bf16_t* __restrict__ kbase,
                                  const bf16_t* __restrict__ vbase,
                                  bf16x8 qlo, bf16x8 qhi,
                                  f32x4* o, float& lrun) {
    // prime K(0)
    bf16x8 kc[8];
#pragma unroll
    for (int n = 0; n < 4; n++) {
        kc[2 * n] = *(const bf16x8*)(kbase + (size_t)(n * 2) * 512);
        kc[2 * n + 1] = *(const bf16x8*)(kbase + (size_t)(n * 2 + 1) * 512);
    }

    for (int kb = 0; kb <= qt; kb++) {
        bf16x8 vv[2][4];
#pragma unroll
        for (int hh = 0; hh < 2; hh++)
#pragma unroll
            for (int n = 0; n < 4; n++)
                vv[hh][n] = *(const bf16x8*)(vbase +
                    (size_t)((kb * 2 + hh) * 4 + n) * 512);

        const int kbn = (kb < qt) ? kb + 1 : kb;
        bf16x8 kn[8];
#pragma unroll
        for (int n = 0; n < 4; n++) {
            kn[2 * n] = *(const bf16x8*)(kbase + (size_t)((kbn * 4 + n) * 2) * 512);
            kn[2 * n + 1] = *(const bf16x8*)(kbase + (size_t)((kbn * 4 + n) * 2 + 1) * 512);
        }

        const int u0 = kb * 64;
        f32x4 s[4];
#pragma unroll
        for (int n = 0; n < 4; n++) {
            const f32x4 z = {};
            s[n] = MFMA16(kc[2 * n], qlo, z);
            s[n] = MFMA16(kc[2 * n + 1], qhi, s[n]);
        }

        if (kb == qt) {  // diagonal 64-key block: causal mask (key > query)
#pragma unroll
            for (int n = 0; n < 4; n++)
#pragma unroll
                for (int r = 0; r < 4; r++)
                    if (u0 + n * 16 + quad * 4 + r > query) s[n][r] = -1e9f;
        }

        f32x4 p[4];
#pragma unroll
        for (int n = 0; n < 4; n++)
#pragma unroll
            for (int r = 0; r < 4; r++) p[n][r] = EXP2(s[n][r]);

        lrun += ((p[0][0] + p[0][1]) + (p[0][2] + p[0][3])) +
                ((p[1][0] + p[1][1]) + (p[1][2] + p[1][3])) +
                ((p[2][0] + p[2][1]) + (p[2][2] + p[2][3])) +
                ((p[3][0] + p[3][1]) + (p[3][2] + p[3][3]));

        bf16x4 pb[4];
#pragma unroll
        for (int n = 0; n < 4; n++)
#pragma unroll
            for (int r = 0; r < 4; r++) pb[n][r] = (bf16_t)p[n][r];

#pragma unroll
        for (int hh = 0; hh < 2; hh++) {  // 32-key halves
            bf16x8 pf;
#if __has_builtin(__builtin_amdgcn_permlane16_swap) && \
    __has_builtin(__builtin_amdgcn_permlane32_swap)
            const u32x2 P0 = as2(pb[2 * hh]);
            const u32x2 P1 = as2(pb[2 * hh + 1]);
            const u32x2 s1a = __builtin_amdgcn_permlane16_swap(P0[0], P0[1], false, false);
            const u32x2 s1b = __builtin_amdgcn_permlane16_swap(P1[0], P1[1], false, false);
            const u32x2 s2a = __builtin_amdgcn_permlane32_swap(s1a[0], s1b[0], false, false);
            const u32x2 s2b = __builtin_amdgcn_permlane32_swap(s1a[1], s1b[1], false, false);
            const u32x2 s3a = __builtin_amdgcn_permlane16_swap(s2a[0], s2a[1], false, false);
            const u32x2 s3b = __builtin_amdgcn_permlane16_swap(s2b[0], s2b[1], false, false);
            const unsigned pfd[4] = {s3a[0], s3a[1], s3b[0], s3b[1]};
            __builtin_memcpy(&pf, pfd, 16);
#else
            const int srcLow = ((quad & 1) << 5) + lr;
            const int srcHigh = srcLow + 16;
            const bool loSel = (quad < 2);
            const bf16x4 a0 = shfl4(pb[2 * hh], srcLow);
            const bf16x4 a1 = shfl4(pb[2 * hh + 1], srcLow);
            const bf16x4 b0 = shfl4(pb[2 * hh], srcHigh);
            const bf16x4 b1 = shfl4(pb[2 * hh + 1], srcHigh);
            const bf16x4 lo = loSel ? a0 : a1;
            const bf16x4 hi = loSel ? b0 : b1;
#pragma unroll
            for (int r = 0; r < 4; r++) { pf[r] = lo[r]; pf[4 + r] = hi[r]; }
#endif
#pragma unroll
            for (int n = 0; n < 4; n++)
                o[n] = MFMA16(vv[hh][n], pf, o[n]);
        }

#pragma unroll
        for (int i = 0; i < 8; i++) kc[i] = kn[i];
    }
}

// ---------------------------------------------------------------------------
// Flash attention, paired tiles for perfect load balance: 512 WGs, WG =
// (pr, bh) handles qt = pr AND qt = 31-pr -> every WG exactly 33 iterations,
// every CU identical (2 WGs x 33). 4 independent waves, no barriers, no LDS.
// ---------------------------------------------------------------------------
__global__ __launch_bounds__(256) void attn_kernel(const bf16_t* __restrict__ q_ws,
                                                   const bf16_t* __restrict__ k_ws,
                                                   const bf16_t* __restrict__ v_ws,
                                                   bf16_t* __restrict__ ctx) {
    const int tid = threadIdx.x;
    const int w = tid >> 6;
    const int lane = tid & 63;
    const int lr = lane & 15;
    const int quad = lane >> 4;
    const int bh = blockIdx.x & 31;
    const int pr = blockIdx.x >> 5;  // 0..15
    const int b = bh >> 4;
    const int hd = bh & 15;

    const bf16_t* kbase = k_ws + (size_t)bh * 131072 + lane * 8;
    const bf16_t* vbase = v_ws + (size_t)bh * 131072 + lane * 8;

#pragma unroll
    for (int half = 0; half < 2; half++) {
        const int qt = half ? (31 - pr) : pr;
        const int trow = qt * 64 + w * 16;
        const int query = trow + lr;

        const bf16_t* qb = q_ws + ((size_t)bh * 2048 + trow + lr) * 64 + quad * 8;
        const bf16x8 qlo = *(const bf16x8*)qb;
        const bf16x8 qhi = *(const bf16x8*)(qb + 32);

        f32x4 o[4] = {};
        float lrun = 0.0f;
        flash_tile(qt, quad, lr, query, kbase, vbase, qlo, qhi, o, lrun);

        lrun += __shfl_xor(lrun, 16);
        lrun += __shfl_xor(lrun, 32);

        const float inv = 1.0f / fmaxf(lrun, 1e-30f);
        const size_t base = ((size_t)b * 2048 + query) * 1024 + hd * 64 + quad * 4;
#pragma unroll
        for (int n = 0; n < 4; n++) {
            bf16x4 ob;
#pragma unroll
            for (int r = 0; r < 4; r++) ob[r] = (bf16_t)(o[n][r] * inv);
            *(bf16x4*)&ctx[base + n * 16] = ob;
        }
    }
}

// ---------------------------------------------------------------------------
// Launcher. Inputs fp32, output fp32.
// ws bytes: [0,8M) hs_b -> (after gemm1) ctx overlay | [8M,14M) wqkv_b |
//           [14M,16M) wo_b | [16M,24M) q | [24M,32M) k | [32M,40M) v.
// ---------------------------------------------------------------------------
extern "C" void kernel_launch(void* const* d_in, const int* in_sizes, int n_in,
                              void* d_out, int out_size, void* d_ws, size_t ws_size,
                              hipStream_t stream) {
    const float* hs = (const float*)d_in[0];
    const float* cosb = (const float*)d_in[1];
    const float* sinb = (const float*)d_in[2];
    const float* wqkv = (const float*)d_in[3];
    const float* wo = (const float*)d_in[4];
    float* out = (float*)d_out;

    char* ws = (char*)d_ws;
    bf16_t* hs_b = (bf16_t*)(ws);
    bf16_t* wqkv_b = hs_b + 4194304;
    bf16_t* wo_b = hs_b + 7340032;
    bf16_t* q_ws = (bf16_t*)(ws + (size_t)(16u << 20));
    bf16_t* k_ws = (bf16_t*)(ws + (size_t)(24u << 20));
    bf16_t* v_ws = (bf16_t*)(ws + (size_t)(32u << 20));
    bf16_t* ctx = (bf16_t*)(ws);  // overlays hs_b (dead after gemm1)

    const dim3 blk(256);

    // 0) fp32 -> bf16 convert (hs | wqkv | wo packed)
    convert_kernel<<<dim3(4096), blk, 0, stream>>>(hs, wqkv, wo, hs_b);

    // 1) QKV projection + fused RoPE + scatter: M=4096, N=3072, K=1024
    gemm_bt<1, 3072, 128><<<dim3(24, 32), blk, 0, stream>>>(
        hs_b, wqkv_b, nullptr, q_ws, k_ws, v_ws, cosb, sinb);

    // 2) Flash attention (paired tiles) -> ctx [B,T,1024] (bf16)
    attn_kernel<<<dim3(512), blk, 0, stream>>>(q_ws, k_ws, v_ws, ctx);

    // 3) Output projection: M=4096, N=1024, K=1024 (BM=64 -> 512 blocks)
    gemm_bt<0, 1024, 64><<<dim3(8, 64), blk, 0, stream>>>(
        ctx, wo_b, out, nullptr, nullptr, nullptr, nullptr, nullptr);
}